// Round 1
// 496.835 us; speedup vs baseline: 1.1926x; 1.1926x over previous
//
#include <hip/hip_runtime.h>
#include <stdint.h>

#define BB 32
#define NN 2048
#define HH 128
#define BN (BB*NN)

typedef short v8s __attribute__((ext_vector_type(8)));
typedef float v4f __attribute__((ext_vector_type(4)));

__device__ __forceinline__ unsigned short f2b(float f){
  union { float f; unsigned int i; } v; v.f = f;
  unsigned int x = v.i;
  unsigned int r = x + 0x7FFFu + ((x >> 16) & 1u);   // RNE f32 -> bf16
  return (unsigned short)(r >> 16);
}
__device__ __forceinline__ unsigned int pk2(float a, float b){
  return (unsigned int)f2b(a) | ((unsigned int)f2b(b) << 16);
}
__device__ __forceinline__ float sigm(float x){ return 1.0f / (1.0f + __expf(-x)); }

// ---------------- pre-swizzle B = [Wi;Wh] (f32) into bf16 MFMA fragment order
// Bsw[((kc*32+ct)*64 + lane)*8 + j] = bf16(Bcat[kc*32 + (lane>>4)*8 + j][ct*16 + (lane&15)])
__global__ void kswz(const float* __restrict__ Wi0, const float* __restrict__ Wh0,
                     const float* __restrict__ Wi1, const float* __restrict__ Wh1,
                     unsigned short* __restrict__ Bsw0, unsigned short* __restrict__ Bsw1){
  int bid = blockIdx.x;            // 0..511
  int layer = bid >> 8;
  int kc = (bid >> 5) & 7;
  int ct = bid & 31;
  int lane = threadIdx.x;          // 0..63
  const float* Wi = layer ? Wi1 : Wi0;
  const float* Wh = layer ? Wh1 : Wh0;
  unsigned short* dst = layer ? Bsw1 : Bsw0;
  int col = ct*16 + (lane & 15);
  int kbase = kc*32 + (lane >> 4)*8;
  size_t o = ((size_t)(kc*32 + ct)*64 + (size_t)lane)*8;
  #pragma unroll
  for (int j = 0; j < 8; j++){
    int k = kbase + j;
    dst[o + j] = f2b((k < 128) ? Wi[k*512 + col] : Wh[(k-128)*512 + col]);
  }
}

// ---------------- save exit/raise rows of old states ------------------------
__global__ void ksave(const float* __restrict__ c0, const float* __restrict__ h0,
                      const float* __restrict__ c1, const float* __restrict__ h1,
                      const int* __restrict__ exit_idx, const int* __restrict__ raise_idx,
                      float* __restrict__ saved){
  int b = blockIdx.x, which = blockIdx.y, c = threadIdx.x;   // c: 0..511
  int idx = which ? raise_idx[b] : exit_idx[b];
  size_t row = (size_t)b*NN + idx;
  const float* bufs[4] = {c0, h0, c1, h1};
  saved[((size_t)b*2 + which)*512 + c] = bufs[c >> 7][row*128 + (c & 127)];
}

// ---------------- restore saved rows into (new) states ----------------------
__global__ void krestore(float* c0, float* h0, float* c1, float* h1,
                         const int* __restrict__ exit_idx, const int* __restrict__ raise_idx,
                         const float* __restrict__ saved){
  int b = blockIdx.x, which = blockIdx.y, c = threadIdx.x;
  int idx = which ? raise_idx[b] : exit_idx[b];
  size_t row = (size_t)b*NN + idx;
  float* bufs[4] = {c0, h0, c1, h1};
  bufs[c >> 7][row*128 + (c & 127)] = saved[((size_t)b*2 + which)*512 + c];
}

// ---------------- fused 2-layer LSTM --------------------------------------
// Block: 64 rows, 512 threads (8 waves). Wave w owns channels w*16..w*16+15
// of every gate. A tiles staged in LDS as bf16; layer-0 output h0_new is
// written back into the LDS A tile (cols 0..127) for layer 1.
#define ROWSB 64
#define PA 264   // ushorts/row of A tile: 256 + 8 pad (528 B, %128B != 0 -> 2-way max)
#define PH 136   // ushorts/row of H1 tile: 128 + 8 pad (272 B)

__global__ __launch_bounds__(512, 4) void klstm2(
    const float* __restrict__ ne,
    float* __restrict__ c0, float* __restrict__ h0,
    float* __restrict__ c1, float* __restrict__ h1,
    const unsigned short* __restrict__ Bsw0, const float* __restrict__ b0,
    const unsigned short* __restrict__ Bsw1, const float* __restrict__ b1,
    const int* __restrict__ step_limits, const int* __restrict__ cur_step)
{
  __shared__ unsigned short ldsA[ROWSB*PA];   // [ne | h0_old] -> later [h0_new | h0_old]
  __shared__ unsigned short ldsH[ROWSB*PH];   // h1_old

  int rowbase = blockIdx.x * ROWSB;           // 64 rows, never crosses a batch
  int b = rowbase >> 11;
  if (cur_step[0] >= step_limits[b]) return;  // done batch: keep old states

  int tid = threadIdx.x;
  int wid = tid >> 6, lane = tid & 63;
  int quad = lane >> 4, l16 = lane & 15;

  // ---- cooperative stage: A0 = bf16([ne | h0_old]), H1 = bf16(h1_old) ----
  {
    int srow = tid >> 6;            // wave -> one row per pass
    int scol = (tid & 63) * 4;      // 0..252
    #pragma unroll
    for (int p = 0; p < 8; p++){
      int row = p*8 + srow;
      size_t g = (size_t)(rowbase + row)*128 + (scol & 127);
      const float* src = (scol < 128) ? (ne + g) : (h0 + g);
      float4 v = *(const float4*)src;
      uint2 w; w.x = pk2(v.x, v.y); w.y = pk2(v.z, v.w);
      *(uint2*)&ldsA[row*PA + scol] = w;
    }
    int hrow = tid >> 5;
    int hcol = (tid & 31) * 4;
    #pragma unroll
    for (int p = 0; p < 4; p++){
      int row = p*16 + hrow;
      float4 v = *(const float4*)(h1 + (size_t)(rowbase + row)*128 + hcol);
      uint2 w; w.x = pk2(v.x, v.y); w.y = pk2(v.z, v.w);
      *(uint2*)&ldsH[row*PH + hcol] = w;
    }
  }
  __syncthreads();

  int ch = wid*16 + l16;            // channel within each gate (0..127)

  // ================= layer 0: gates = [ne|h0_old] @ B0 =================
  v4f acc[4][4] = {};               // [row-tile][gate]
  #pragma unroll
  for (int kc = 0; kc < 8; kc++){
    v8s bf0 = ((const v8s*)Bsw0)[(size_t)(kc*32 + 0*8 + wid)*64 + lane];
    v8s bf1 = ((const v8s*)Bsw0)[(size_t)(kc*32 + 1*8 + wid)*64 + lane];
    v8s bf2 = ((const v8s*)Bsw0)[(size_t)(kc*32 + 2*8 + wid)*64 + lane];
    v8s bf3 = ((const v8s*)Bsw0)[(size_t)(kc*32 + 3*8 + wid)*64 + lane];
    #pragma unroll
    for (int rt = 0; rt < 4; rt++){
      v8s a = *(const v8s*)&ldsA[(rt*16 + l16)*PA + kc*32 + quad*8];
      acc[rt][0] = __builtin_amdgcn_mfma_f32_16x16x32_bf16(a, bf0, acc[rt][0], 0,0,0);
      acc[rt][1] = __builtin_amdgcn_mfma_f32_16x16x32_bf16(a, bf1, acc[rt][1], 0,0,0);
      acc[rt][2] = __builtin_amdgcn_mfma_f32_16x16x32_bf16(a, bf2, acc[rt][2], 0,0,0);
      acc[rt][3] = __builtin_amdgcn_mfma_f32_16x16x32_bf16(a, bf3, acc[rt][3], 0,0,0);
    }
  }
  __syncthreads();   // all LDS A reads done before h0_new overwrites cols 0..127

  {
    float bi = b0[ch], bfv = b0[128+ch], bg = b0[256+ch], bo = b0[384+ch];
    #pragma unroll
    for (int rt = 0; rt < 4; rt++){
      #pragma unroll
      for (int r = 0; r < 4; r++){
        int lrow = rt*16 + quad*4 + r;
        size_t row = (size_t)rowbase + lrow;
        float iv = acc[rt][0][r] + bi;
        float fv = acc[rt][1][r] + bfv;
        float gv = acc[rt][2][r] + bg;
        float ov = acc[rt][3][r] + bo;
        float cold = c0[row*128 + ch];
        float cn = sigm(fv)*cold + sigm(iv)*tanhf(gv);
        float hn = sigm(ov)*tanhf(cn);
        c0[row*128 + ch] = cn;
        h0[row*128 + ch] = hn;
        ldsA[lrow*PA + ch] = f2b(hn);   // layer-1 A operand, cols 0..127
      }
    }
  }
  __syncthreads();

  // ================= layer 1: gates = [h0_new | h1_old] @ B1 =================
  #pragma unroll
  for (int rt = 0; rt < 4; rt++)
    #pragma unroll
    for (int g = 0; g < 4; g++)
      acc[rt][g] = (v4f){0.f, 0.f, 0.f, 0.f};

  #pragma unroll
  for (int kc = 0; kc < 8; kc++){
    v8s bf0 = ((const v8s*)Bsw1)[(size_t)(kc*32 + 0*8 + wid)*64 + lane];
    v8s bf1 = ((const v8s*)Bsw1)[(size_t)(kc*32 + 1*8 + wid)*64 + lane];
    v8s bf2 = ((const v8s*)Bsw1)[(size_t)(kc*32 + 2*8 + wid)*64 + lane];
    v8s bf3 = ((const v8s*)Bsw1)[(size_t)(kc*32 + 3*8 + wid)*64 + lane];
    #pragma unroll
    for (int rt = 0; rt < 4; rt++){
      v8s a = (kc < 4)
        ? *(const v8s*)&ldsA[(rt*16 + l16)*PA + kc*32 + quad*8]
        : *(const v8s*)&ldsH[(rt*16 + l16)*PH + (kc-4)*32 + quad*8];
      acc[rt][0] = __builtin_amdgcn_mfma_f32_16x16x32_bf16(a, bf0, acc[rt][0], 0,0,0);
      acc[rt][1] = __builtin_amdgcn_mfma_f32_16x16x32_bf16(a, bf1, acc[rt][1], 0,0,0);
      acc[rt][2] = __builtin_amdgcn_mfma_f32_16x16x32_bf16(a, bf2, acc[rt][2], 0,0,0);
      acc[rt][3] = __builtin_amdgcn_mfma_f32_16x16x32_bf16(a, bf3, acc[rt][3], 0,0,0);
    }
  }

  {
    float bi = b1[ch], bfv = b1[128+ch], bg = b1[256+ch], bo = b1[384+ch];
    #pragma unroll
    for (int rt = 0; rt < 4; rt++){
      #pragma unroll
      for (int r = 0; r < 4; r++){
        size_t row = (size_t)rowbase + rt*16 + quad*4 + r;
        float iv = acc[rt][0][r] + bi;
        float fv = acc[rt][1][r] + bfv;
        float gv = acc[rt][2][r] + bg;
        float ov = acc[rt][3][r] + bo;
        float cold = c1[row*128 + ch];
        float cn = sigm(fv)*cold + sigm(iv)*tanhf(gv);
        float hn = sigm(ov)*tanhf(cn);
        c1[row*128 + ch] = cn;
        h1[row*128 + ch] = hn;
      }
    }
  }
}

// ---------------- decisions: softmax(hs @ W) -> edge weights wr/wt/wf -------
__global__ __launch_bounds__(256) void kdec(
    const float* __restrict__ c0, const float* __restrict__ h0,
    const float* __restrict__ c1, const float* __restrict__ h1,
    const float* __restrict__ Wr, const float* __restrict__ br,
    const float* __restrict__ Wb, const float* __restrict__ bb,
    const float* __restrict__ ip,
    const int* __restrict__ exit_idx, const int* __restrict__ raise_idx,
    float* __restrict__ wbuf)
{
  int tid = threadIdx.x;
  int wid = tid >> 6, lane = tid & 63;
  int gid = blockIdx.x*4 + wid;          // node id
  int b = gid >> 11, n = gid & 2047;

  const float* bufs[4] = {c0, h0, c1, h1};
  const float* hb = bufs[lane >> 4] + (size_t)gid*128 + (lane & 15)*8;
  float4 hv0 = *(const float4*)hb;
  float4 hv1 = *(const float4*)(hb + 4);
  float hv[8] = {hv0.x, hv0.y, hv0.z, hv0.w, hv1.x, hv1.y, hv1.z, hv1.w};
  const float* wrp = Wr + lane*16;
  const float* wbp = Wb + lane*16;
  float r0=0.f, r1=0.f, q0=0.f, q1=0.f;
  #pragma unroll
  for (int j = 0; j < 8; j++){
    float h = hv[j];
    r0 += h * wrp[j*2];  r1 += h * wrp[j*2+1];
    q0 += h * wbp[j*2];  q1 += h * wbp[j*2+1];
  }
  #pragma unroll
  for (int off = 32; off > 0; off >>= 1){
    r0 += __shfl_xor(r0, off, 64);
    r1 += __shfl_xor(r1, off, 64);
    q0 += __shfl_xor(q0, off, 64);
    q1 += __shfl_xor(q1, off, 64);
  }
  if (lane == 0){
    r0 += br[0]; r1 += br[1];
    q0 += bb[0]; q1 += bb[1];
    float pr, pn;
    if (n == exit_idx[b] || n == raise_idx[b]){ pr = 0.f; pn = 1.f; }
    else {
      float m = fmaxf(r0, r1);
      float e0 = __expf(r0 - m), e1 = __expf(r1 - m);
      pr = e0 / (e0 + e1); pn = e1 / (e0 + e1);
    }
    float m2 = fmaxf(q0, q1);
    float f0 = __expf(q0 - m2), f1 = __expf(q1 - m2);
    float pt = f0 / (f0 + f1), pf = f1 / (f0 + f1);
    float ipv = ip[gid];
    wbuf[0*BN + gid] = pr * ipv;
    wbuf[1*BN + gid] = pn * pt * ipv;
    wbuf[2*BN + gid] = pn * pf * ipv;
  }
}

// ---------------- CSR build: count / scan / fill ----------------------------
__global__ void kcount(const int* __restrict__ ri, const int* __restrict__ ti,
                       const int* __restrict__ fi, int* __restrict__ counts){
  int gid = blockIdx.x*256 + threadIdx.x;
  int base = (gid >> 11) << 11;
  atomicAdd(&counts[base + ri[gid]], 1);
  atomicAdd(&counts[base + ti[gid]], 1);
  atomicAdd(&counts[base + fi[gid]], 1);
}

__global__ __launch_bounds__(256) void kscan(const int* __restrict__ counts,
                                             int* __restrict__ offsets){
  __shared__ int lds[256];
  int b = blockIdx.x, tid = threadIdx.x;
  const int* c = counts + b*NN;
  int* o = offsets + b*NN;
  int v[8]; int s = 0;
  #pragma unroll
  for (int i = 0; i < 8; i++){ v[i] = c[tid*8+i]; s += v[i]; }
  lds[tid] = s;
  __syncthreads();
  if (tid == 0){
    int run = 0;
    for (int t = 0; t < 256; t++){ int tmp = lds[t]; lds[t] = run; run += tmp; }
  }
  __syncthreads();
  int off = lds[tid];
  #pragma unroll
  for (int i = 0; i < 8; i++){ o[tid*8+i] = off; off += v[i]; }
}

__global__ void kfill(const int* __restrict__ ri, const int* __restrict__ ti,
                      const int* __restrict__ fi, const int* __restrict__ offsets,
                      int* __restrict__ cursor, unsigned short* __restrict__ edges){
  int gid = blockIdx.x*256 + threadIdx.x;
  int b = gid >> 11, n = gid & 2047;
  size_t ebase = (size_t)b*3*NN;
  int t0 = ri[gid]; int p0 = atomicAdd(&cursor[b*NN+t0], 1);
  edges[ebase + offsets[b*NN+t0] + p0] = (unsigned short)(n);
  int t1 = ti[gid]; int p1 = atomicAdd(&cursor[b*NN+t1], 1);
  edges[ebase + offsets[b*NN+t1] + p1] = (unsigned short)(n | (1<<11));
  int t2 = fi[gid]; int p2 = atomicAdd(&cursor[b*NN+t2], 1);
  edges[ebase + offsets[b*NN+t2] + p2] = (unsigned short)(n | (2<<11));
}

// ---------------- gather + normalize + output (all batches) -----------------
// done batches: states were never updated (klstm2 skipped them), so this
// block just copies old state + old ip (former kearly).
__global__ __launch_bounds__(128) void kagg(
    const float* __restrict__ c0, const float* __restrict__ h0,
    const float* __restrict__ c1, const float* __restrict__ h1,
    const float* __restrict__ ip,
    const float* __restrict__ wbuf, const unsigned short* __restrict__ edges,
    const int* __restrict__ counts, const int* __restrict__ offsets,
    const int* __restrict__ step_limits, const int* __restrict__ cur_step,
    float* __restrict__ out)
{
  int gid = blockIdx.x;            // b*N + j
  int b = gid >> 11;
  int tid = threadIdx.x;           // 0..127, channels tid*4..tid*4+3
  size_t obase = (size_t)gid*513;
  const float* bufs[4] = {c0, h0, c1, h1};

  if (cur_step[0] >= step_limits[b]){       // done: copy old state + old ip
    int c = tid*4;
    const float* s = bufs[c >> 7];
    size_t rb = (size_t)gid*128 + (c & 127);
    out[obase + c+0] = s[rb+0];
    out[obase + c+1] = s[rb+1];
    out[obase + c+2] = s[rb+2];
    out[obase + c+3] = s[rb+3];
    if (tid == 0) out[obase + 512] = ip[gid];
    return;
  }

  int cnt = counts[gid], off = offsets[gid];
  const unsigned short* eb = edges + (size_t)b*3*NN + off;
  const float* sb = bufs[tid >> 5];
  int coff = (tid & 31)*4;
  float a0=0.f, a1=0.f, a2=0.f, a3=0.f, ipn=0.f;
  for (int e = 0; e < cnt; e++){
    int pk = eb[e];
    int n = pk & 2047, et = pk >> 11;
    float w = wbuf[et*BN + (b<<11) + n];
    ipn += w;
    float4 sv = *(const float4*)(sb + ((size_t)(b<<11) + n)*128 + coff);
    a0 += w * sv.x;
    a1 += w * sv.y;
    a2 += w * sv.z;
    a3 += w * sv.w;
  }
  int c = tid*4;
  float inv = 1.0f / (ipn + 1e-7f);
  out[obase + c+0] = a0*inv;
  out[obase + c+1] = a1*inv;
  out[obase + c+2] = a2*inv;
  out[obase + c+3] = a3*inv;
  if (tid == 0) out[obase + 512] = ipn;
}

extern "C" void kernel_launch(void* const* d_in, const int* in_sizes, int n_in,
                              void* d_out, int out_size, void* d_ws, size_t ws_size,
                              hipStream_t stream){
  const float* ne  = (const float*)d_in[0];
  float* c0  = (float*)d_in[1];   // updated in place (harness restores before every launch)
  float* h0  = (float*)d_in[2];
  float* c1  = (float*)d_in[3];
  float* h1  = (float*)d_in[4];
  const float* ip  = (const float*)d_in[5];
  const float* Wi0 = (const float*)d_in[6];
  const float* Wh0 = (const float*)d_in[7];
  const float* b0  = (const float*)d_in[8];
  const float* Wi1 = (const float*)d_in[9];
  const float* Wh1 = (const float*)d_in[10];
  const float* b1  = (const float*)d_in[11];
  const float* Wr  = (const float*)d_in[12];
  const float* br  = (const float*)d_in[13];
  const float* Wb  = (const float*)d_in[14];
  const float* bb  = (const float*)d_in[15];
  const int* ti  = (const int*)d_in[16];
  const int* fi  = (const int*)d_in[17];
  const int* ri  = (const int*)d_in[18];
  const int* ei  = (const int*)d_in[19];
  const int* rni = (const int*)d_in[20];
  const int* sl  = (const int*)d_in[21];
  const int* cs  = (const int*)d_in[22];
  float* out = (float*)d_out;

  // --- ws layout (total ~2.5 MB) ---
  uint8_t* ws = (uint8_t*)d_ws;
  unsigned short* Bsw0    = (unsigned short*)(ws + 0);         // 262144 B
  unsigned short* Bsw1    = (unsigned short*)(ws + 262144);    // 262144 B
  float*          saved   = (float*)(ws + 524288);             // 131072 B
  float*          wbuf    = (float*)(ws + 655360);             // 786432 B
  int*            counts  = (int*)(ws + 1441792);              // 262144 B
  int*            offsets = (int*)(ws + 1703936);              // 262144 B
  int*            cursor  = (int*)(ws + 1966080);              // 262144 B
  unsigned short* edges   = (unsigned short*)(ws + 2228224);   // 393216 B

  hipMemsetAsync(counts, 0, BN*sizeof(int), stream);
  hipMemsetAsync(cursor, 0, BN*sizeof(int), stream);

  kswz<<<512, 64, 0, stream>>>(Wi0, Wh0, Wi1, Wh1, Bsw0, Bsw1);
  ksave<<<dim3(BB, 2), 512, 0, stream>>>(c0, h0, c1, h1, ei, rni, saved);

  // fused 2-layer LSTM, in place; skips done batches (they keep old states)
  klstm2<<<BN/ROWSB, 512, 0, stream>>>(ne, c0, h0, c1, h1, Bsw0, b0, Bsw1, b1, sl, cs);

  krestore<<<dim3(BB, 2), 512, 0, stream>>>(c0, h0, c1, h1, ei, rni, saved);

  kdec<<<BN/4, 256, 0, stream>>>(c0, h0, c1, h1, Wr, br, Wb, bb, ip, ei, rni, wbuf);

  kcount<<<BN/256, 256, 0, stream>>>(ri, ti, fi, counts);
  kscan<<<BB, 256, 0, stream>>>(counts, offsets);
  kfill<<<BN/256, 256, 0, stream>>>(ri, ti, fi, offsets, cursor, edges);

  kagg<<<BN, 128, 0, stream>>>(c0, h0, c1, h1, ip, wbuf, edges, counts, offsets,
                               sl, cs, out);
}

// Round 2
// 463.518 us; speedup vs baseline: 1.2783x; 1.0719x over previous
//
#include <hip/hip_runtime.h>
#include <stdint.h>

#define BB 32
#define NN 2048
#define HH 128
#define BN (BB*NN)

typedef short v8s __attribute__((ext_vector_type(8)));
typedef float v4f __attribute__((ext_vector_type(4)));

__device__ __forceinline__ unsigned short f2b(float f){
  union { float f; unsigned int i; } v; v.f = f;
  unsigned int x = v.i;
  unsigned int r = x + 0x7FFFu + ((x >> 16) & 1u);   // RNE f32 -> bf16
  return (unsigned short)(r >> 16);
}
__device__ __forceinline__ unsigned int pk2(float a, float b){
  return (unsigned int)f2b(a) | ((unsigned int)f2b(b) << 16);
}
__device__ __forceinline__ float frcp(float x){ return __builtin_amdgcn_rcpf(x); }
// fast sigmoid / tanh: v_exp + v_rcp, ~1e-6 rel err (<< bf16 gate noise)
__device__ __forceinline__ float fsigm(float x){ return frcp(1.0f + __expf(-x)); }
__device__ __forceinline__ float ftanh(float x){ return 1.0f - 2.0f*frcp(1.0f + __expf(2.0f*x)); }

// ---------------- pre-swizzle B = [Wi;Wh] (f32) into bf16 MFMA fragment order
// Bsw[((kc*32+ct)*64 + lane)*8 + j] = bf16(Bcat[kc*32 + (lane>>4)*8 + j][ct*16 + (lane&15)])
__global__ void kswz(const float* __restrict__ Wi0, const float* __restrict__ Wh0,
                     const float* __restrict__ Wi1, const float* __restrict__ Wh1,
                     unsigned short* __restrict__ Bsw0, unsigned short* __restrict__ Bsw1){
  int bid = blockIdx.x;            // 0..511
  int layer = bid >> 8;
  int kc = (bid >> 5) & 7;
  int ct = bid & 31;
  int lane = threadIdx.x;          // 0..63
  const float* Wi = layer ? Wi1 : Wi0;
  const float* Wh = layer ? Wh1 : Wh0;
  unsigned short* dst = layer ? Bsw1 : Bsw0;
  int col = ct*16 + (lane & 15);
  int kbase = kc*32 + (lane >> 4)*8;
  size_t o = ((size_t)(kc*32 + ct)*64 + (size_t)lane)*8;
  #pragma unroll
  for (int j = 0; j < 8; j++){
    int k = kbase + j;
    dst[o + j] = f2b((k < 128) ? Wi[k*512 + col] : Wh[(k-128)*512 + col]);
  }
}

// ---------------- save exit/raise rows of old states ------------------------
__global__ void ksave(const float* __restrict__ c0, const float* __restrict__ h0,
                      const float* __restrict__ c1, const float* __restrict__ h1,
                      const int* __restrict__ exit_idx, const int* __restrict__ raise_idx,
                      float* __restrict__ saved){
  int b = blockIdx.x, which = blockIdx.y, c = threadIdx.x;   // c: 0..511
  int idx = which ? raise_idx[b] : exit_idx[b];
  size_t row = (size_t)b*NN + idx;
  const float* bufs[4] = {c0, h0, c1, h1};
  saved[((size_t)b*2 + which)*512 + c] = bufs[c >> 7][row*128 + (c & 127)];
}

// ---------------- restore saved rows into (new) states ----------------------
__global__ void krestore(float* c0, float* h0, float* c1, float* h1,
                         const int* __restrict__ exit_idx, const int* __restrict__ raise_idx,
                         const float* __restrict__ saved){
  int b = blockIdx.x, which = blockIdx.y, c = threadIdx.x;
  int idx = which ? raise_idx[b] : exit_idx[b];
  size_t row = (size_t)b*NN + idx;
  float* bufs[4] = {c0, h0, c1, h1};
  bufs[c >> 7][row*128 + (c & 127)] = saved[((size_t)b*2 + which)*512 + c];
}

// ---------------- fused 2-layer LSTM --------------------------------------
// Block: 32 rows, 512 threads (8 waves). Wave w owns channels w*16..w*16+15 of
// every gate (acc[2 rt][4 gates] = 32 regs/thread). A tiles staged in LDS as
// bf16. h0_new goes to a SEPARATE LDS region (ldsG) so no barrier is needed
// between GEMM0 reads and epilogue-0 writes. 2 barriers total.
#define ROWSB 32
#define PA 264   // ushorts/row of A tile: 256 + 8 pad (528 B -> 2-way max on b128)
#define PH 136   // ushorts/row of H tiles: 128 + 8 pad (272 B)

__global__ __launch_bounds__(512, 4) void klstm2(
    const float* __restrict__ ne,
    float* __restrict__ c0, float* __restrict__ h0,
    float* __restrict__ c1, float* __restrict__ h1,
    const unsigned short* __restrict__ Bsw0, const float* __restrict__ b0,
    const unsigned short* __restrict__ Bsw1, const float* __restrict__ b1,
    const int* __restrict__ step_limits, const int* __restrict__ cur_step)
{
  __shared__ unsigned short ldsA[ROWSB*PA];   // [ne | h0_old] bf16
  __shared__ unsigned short ldsH[ROWSB*PH];   // h1_old bf16
  __shared__ unsigned short ldsG[ROWSB*PH];   // h0_new bf16

  int rowbase = blockIdx.x * ROWSB;           // 32 rows, never crosses a batch
  int b = rowbase >> 11;
  if (cur_step[0] >= step_limits[b]) return;  // done batch: keep old states

  int tid = threadIdx.x;
  int wid = tid >> 6, lane = tid & 63;
  int quad = lane >> 4, l16 = lane & 15;
  int ch = wid*16 + l16;            // channel within each gate (0..127)

  // ---- stage A0 = bf16([ne | h0_old]) : 4 float4 per thread ----
  #pragma unroll
  for (int p = 0; p < 4; p++){
    int idx = p*512 + tid;
    int row = idx >> 6, chunk = idx & 63;     // chunk = float4 index (0..63)
    size_t g = (size_t)(rowbase + row)*128 + (chunk & 31)*4;
    float4 v = (chunk < 32) ? *(const float4*)(ne + g) : *(const float4*)(h0 + g);
    uint2 w; w.x = pk2(v.x, v.y); w.y = pk2(v.z, v.w);
    *(uint2*)&ldsA[row*PA + chunk*4] = w;
  }
  __syncthreads();

  // ---- prefetch c0 rows + layer-0 biases (independent of LDS; hidden by GEMM0)
  float cpre[8], bias[4];
  #pragma unroll
  for (int rt = 0; rt < 2; rt++)
    #pragma unroll
    for (int r = 0; r < 4; r++)
      cpre[rt*4+r] = c0[((size_t)rowbase + rt*16 + quad*4 + r)*128 + ch];
  #pragma unroll
  for (int g = 0; g < 4; g++) bias[g] = b0[g*128 + ch];

  // ---- stage H1 = bf16(h1_old) during GEMM0's shadow (consumed after b2) ----
  #pragma unroll
  for (int p = 0; p < 2; p++){
    int idx = p*512 + tid;
    int row = idx >> 5, chunk = idx & 31;
    float4 v = *(const float4*)(h1 + (size_t)(rowbase + row)*128 + chunk*4);
    uint2 w; w.x = pk2(v.x, v.y); w.y = pk2(v.z, v.w);
    *(uint2*)&ldsH[row*PH + chunk*4] = w;
  }

  // ================= layer 0: gates = [ne|h0_old] @ B0 =================
  const v8s* Bv0 = (const v8s*)Bsw0;
  v4f acc[2][4] = {};
  v8s bc[4], bn[4];
  #pragma unroll
  for (int g = 0; g < 4; g++) bc[g] = Bv0[(size_t)(g*8 + wid)*64 + lane];
  #pragma unroll
  for (int kc = 0; kc < 8; kc++){
    if (kc < 7){
      #pragma unroll
      for (int g = 0; g < 4; g++) bn[g] = Bv0[(size_t)((kc+1)*32 + g*8 + wid)*64 + lane];
    }
    v8s a0 = *(const v8s*)&ldsA[(0*16 + l16)*PA + kc*32 + quad*8];
    v8s a1 = *(const v8s*)&ldsA[(1*16 + l16)*PA + kc*32 + quad*8];
    #pragma unroll
    for (int g = 0; g < 4; g++){
      acc[0][g] = __builtin_amdgcn_mfma_f32_16x16x32_bf16(a0, bc[g], acc[0][g], 0,0,0);
      acc[1][g] = __builtin_amdgcn_mfma_f32_16x16x32_bf16(a1, bc[g], acc[1][g], 0,0,0);
    }
    #pragma unroll
    for (int g = 0; g < 4; g++) bc[g] = bn[g];
  }

  // ---- epilogue 0: LSTM update, h0_new -> ldsG (separate region, no barrier)
  #pragma unroll
  for (int rt = 0; rt < 2; rt++){
    #pragma unroll
    for (int r = 0; r < 4; r++){
      int lrow = rt*16 + quad*4 + r;
      size_t row = (size_t)rowbase + lrow;
      float iv = acc[rt][0][r] + bias[0];
      float fv = acc[rt][1][r] + bias[1];
      float gv = acc[rt][2][r] + bias[2];
      float ov = acc[rt][3][r] + bias[3];
      float cold = cpre[rt*4+r];
      float cn = fsigm(fv)*cold + fsigm(iv)*ftanh(gv);
      float hn = fsigm(ov)*ftanh(cn);
      c0[row*128 + ch] = cn;
      h0[row*128 + ch] = hn;
      ldsG[lrow*PH + ch] = f2b(hn);
    }
  }
  __syncthreads();   // h0_new + h1_old LDS tiles complete

  // ---- prefetch c1 rows + layer-1 biases (hidden by GEMM1) ----
  #pragma unroll
  for (int rt = 0; rt < 2; rt++)
    #pragma unroll
    for (int r = 0; r < 4; r++)
      cpre[rt*4+r] = c1[((size_t)rowbase + rt*16 + quad*4 + r)*128 + ch];
  #pragma unroll
  for (int g = 0; g < 4; g++) bias[g] = b1[g*128 + ch];

  // ================= layer 1: gates = [h0_new | h1_old] @ B1 =================
  const v8s* Bv1 = (const v8s*)Bsw1;
  #pragma unroll
  for (int rt = 0; rt < 2; rt++)
    #pragma unroll
    for (int g = 0; g < 4; g++)
      acc[rt][g] = (v4f){0.f, 0.f, 0.f, 0.f};
  #pragma unroll
  for (int g = 0; g < 4; g++) bc[g] = Bv1[(size_t)(g*8 + wid)*64 + lane];
  #pragma unroll
  for (int kc = 0; kc < 8; kc++){
    if (kc < 7){
      #pragma unroll
      for (int g = 0; g < 4; g++) bn[g] = Bv1[(size_t)((kc+1)*32 + g*8 + wid)*64 + lane];
    }
    v8s a0, a1;
    if (kc < 4){
      a0 = *(const v8s*)&ldsG[(0*16 + l16)*PH + kc*32 + quad*8];
      a1 = *(const v8s*)&ldsG[(1*16 + l16)*PH + kc*32 + quad*8];
    } else {
      a0 = *(const v8s*)&ldsH[(0*16 + l16)*PH + (kc-4)*32 + quad*8];
      a1 = *(const v8s*)&ldsH[(1*16 + l16)*PH + (kc-4)*32 + quad*8];
    }
    #pragma unroll
    for (int g = 0; g < 4; g++){
      acc[0][g] = __builtin_amdgcn_mfma_f32_16x16x32_bf16(a0, bc[g], acc[0][g], 0,0,0);
      acc[1][g] = __builtin_amdgcn_mfma_f32_16x16x32_bf16(a1, bc[g], acc[1][g], 0,0,0);
    }
    #pragma unroll
    for (int g = 0; g < 4; g++) bc[g] = bn[g];
  }

  // ---- epilogue 1 ----
  #pragma unroll
  for (int rt = 0; rt < 2; rt++){
    #pragma unroll
    for (int r = 0; r < 4; r++){
      size_t row = (size_t)rowbase + rt*16 + quad*4 + r;
      float iv = acc[rt][0][r] + bias[0];
      float fv = acc[rt][1][r] + bias[1];
      float gv = acc[rt][2][r] + bias[2];
      float ov = acc[rt][3][r] + bias[3];
      float cold = cpre[rt*4+r];
      float cn = fsigm(fv)*cold + fsigm(iv)*ftanh(gv);
      float hn = fsigm(ov)*ftanh(cn);
      c1[row*128 + ch] = cn;
      h1[row*128 + ch] = hn;
    }
  }
}

// ---------------- decisions: softmax(hs @ W) -> edge weights wr/wt/wf -------
// also folds the CSR edge counting (former kcount) into idle lanes
__global__ __launch_bounds__(256) void kdec(
    const float* __restrict__ c0, const float* __restrict__ h0,
    const float* __restrict__ c1, const float* __restrict__ h1,
    const float* __restrict__ Wr, const float* __restrict__ br,
    const float* __restrict__ Wb, const float* __restrict__ bb,
    const float* __restrict__ ip,
    const int* __restrict__ exit_idx, const int* __restrict__ raise_idx,
    const int* __restrict__ ri, const int* __restrict__ ti, const int* __restrict__ fi,
    int* __restrict__ counts,
    float* __restrict__ wbuf)
{
  int tid = threadIdx.x;
  int wid = tid >> 6, lane = tid & 63;
  int gid = blockIdx.x*4 + wid;          // node id
  int b = gid >> 11, n = gid & 2047;

  const float* bufs[4] = {c0, h0, c1, h1};
  const float* hb = bufs[lane >> 4] + (size_t)gid*128 + (lane & 15)*8;
  float4 hv0 = *(const float4*)hb;
  float4 hv1 = *(const float4*)(hb + 4);
  float hv[8] = {hv0.x, hv0.y, hv0.z, hv0.w, hv1.x, hv1.y, hv1.z, hv1.w};
  const float* wrp = Wr + lane*16;
  const float* wbp = Wb + lane*16;
  float r0=0.f, r1=0.f, q0=0.f, q1=0.f;
  #pragma unroll
  for (int j = 0; j < 8; j++){
    float h = hv[j];
    r0 += h * wrp[j*2];  r1 += h * wrp[j*2+1];
    q0 += h * wbp[j*2];  q1 += h * wbp[j*2+1];
  }
  #pragma unroll
  for (int off = 32; off > 0; off >>= 1){
    r0 += __shfl_xor(r0, off, 64);
    r1 += __shfl_xor(r1, off, 64);
    q0 += __shfl_xor(q0, off, 64);
    q1 += __shfl_xor(q1, off, 64);
  }
  if (lane == 0){
    r0 += br[0]; r1 += br[1];
    q0 += bb[0]; q1 += bb[1];
    float pr, pn;
    if (n == exit_idx[b] || n == raise_idx[b]){ pr = 0.f; pn = 1.f; }
    else {
      float m = fmaxf(r0, r1);
      float e0 = __expf(r0 - m), e1 = __expf(r1 - m);
      pr = e0 / (e0 + e1); pn = e1 / (e0 + e1);
    }
    float m2 = fmaxf(q0, q1);
    float f0 = __expf(q0 - m2), f1 = __expf(q1 - m2);
    float pt = f0 / (f0 + f1), pf = f1 / (f0 + f1);
    float ipv = ip[gid];
    wbuf[0*BN + gid] = pr * ipv;
    wbuf[1*BN + gid] = pn * pt * ipv;
    wbuf[2*BN + gid] = pn * pf * ipv;
  } else if (lane == 1){
    atomicAdd(&counts[(b<<11) + ri[gid]], 1);
  } else if (lane == 2){
    atomicAdd(&counts[(b<<11) + ti[gid]], 1);
  } else if (lane == 3){
    atomicAdd(&counts[(b<<11) + fi[gid]], 1);
  }
}

// ---------------- CSR build: scan / fill ------------------------------------
__global__ __launch_bounds__(256) void kscan(const int* __restrict__ counts,
                                             int* __restrict__ offsets){
  __shared__ int lds[256];
  int b = blockIdx.x, tid = threadIdx.x;
  const int* c = counts + b*NN;
  int* o = offsets + b*NN;
  int v[8]; int s = 0;
  #pragma unroll
  for (int i = 0; i < 8; i++){ v[i] = c[tid*8+i]; s += v[i]; }
  lds[tid] = s;
  __syncthreads();
  if (tid == 0){
    int run = 0;
    for (int t = 0; t < 256; t++){ int tmp = lds[t]; lds[t] = run; run += tmp; }
  }
  __syncthreads();
  int off = lds[tid];
  #pragma unroll
  for (int i = 0; i < 8; i++){ o[tid*8+i] = off; off += v[i]; }
}

__global__ void kfill(const int* __restrict__ ri, const int* __restrict__ ti,
                      const int* __restrict__ fi, const int* __restrict__ offsets,
                      int* __restrict__ cursor, unsigned short* __restrict__ edges){
  int gid = blockIdx.x*256 + threadIdx.x;
  int b = gid >> 11, n = gid & 2047;
  size_t ebase = (size_t)b*3*NN;
  int t0 = ri[gid]; int p0 = atomicAdd(&cursor[b*NN+t0], 1);
  edges[ebase + offsets[b*NN+t0] + p0] = (unsigned short)(n);
  int t1 = ti[gid]; int p1 = atomicAdd(&cursor[b*NN+t1], 1);
  edges[ebase + offsets[b*NN+t1] + p1] = (unsigned short)(n | (1<<11));
  int t2 = fi[gid]; int p2 = atomicAdd(&cursor[b*NN+t2], 1);
  edges[ebase + offsets[b*NN+t2] + p2] = (unsigned short)(n | (2<<11));
}

// ---------------- gather + normalize + output (all batches) -----------------
__global__ __launch_bounds__(128) void kagg(
    const float* __restrict__ c0, const float* __restrict__ h0,
    const float* __restrict__ c1, const float* __restrict__ h1,
    const float* __restrict__ ip,
    const float* __restrict__ wbuf, const unsigned short* __restrict__ edges,
    const int* __restrict__ counts, const int* __restrict__ offsets,
    const int* __restrict__ step_limits, const int* __restrict__ cur_step,
    float* __restrict__ out)
{
  int gid = blockIdx.x;            // b*N + j
  int b = gid >> 11;
  int tid = threadIdx.x;           // 0..127, channels tid*4..tid*4+3
  size_t obase = (size_t)gid*513;
  const float* bufs[4] = {c0, h0, c1, h1};

  if (cur_step[0] >= step_limits[b]){       // done: copy old state + old ip
    int c = tid*4;
    const float* s = bufs[c >> 7];
    size_t rb = (size_t)gid*128 + (c & 127);
    out[obase + c+0] = s[rb+0];
    out[obase + c+1] = s[rb+1];
    out[obase + c+2] = s[rb+2];
    out[obase + c+3] = s[rb+3];
    if (tid == 0) out[obase + 512] = ip[gid];
    return;
  }

  int cnt = counts[gid], off = offsets[gid];
  const unsigned short* eb = edges + (size_t)b*3*NN + off;
  const float* sb = bufs[tid >> 5];
  int coff = (tid & 31)*4;
  float a0=0.f, a1=0.f, a2=0.f, a3=0.f, ipn=0.f;
  for (int e = 0; e < cnt; e++){
    int pk = eb[e];
    int n = pk & 2047, et = pk >> 11;
    float w = wbuf[et*BN + (b<<11) + n];
    ipn += w;
    float4 sv = *(const float4*)(sb + ((size_t)(b<<11) + n)*128 + coff);
    a0 += w * sv.x;
    a1 += w * sv.y;
    a2 += w * sv.z;
    a3 += w * sv.w;
  }
  int c = tid*4;
  float inv = 1.0f / (ipn + 1e-7f);
  out[obase + c+0] = a0*inv;
  out[obase + c+1] = a1*inv;
  out[obase + c+2] = a2*inv;
  out[obase + c+3] = a3*inv;
  if (tid == 0) out[obase + 512] = ipn;
}

extern "C" void kernel_launch(void* const* d_in, const int* in_sizes, int n_in,
                              void* d_out, int out_size, void* d_ws, size_t ws_size,
                              hipStream_t stream){
  const float* ne  = (const float*)d_in[0];
  float* c0  = (float*)d_in[1];   // updated in place (harness restores before every launch)
  float* h0  = (float*)d_in[2];
  float* c1  = (float*)d_in[3];
  float* h1  = (float*)d_in[4];
  const float* ip  = (const float*)d_in[5];
  const float* Wi0 = (const float*)d_in[6];
  const float* Wh0 = (const float*)d_in[7];
  const float* b0  = (const float*)d_in[8];
  const float* Wi1 = (const float*)d_in[9];
  const float* Wh1 = (const float*)d_in[10];
  const float* b1  = (const float*)d_in[11];
  const float* Wr  = (const float*)d_in[12];
  const float* br  = (const float*)d_in[13];
  const float* Wb  = (const float*)d_in[14];
  const float* bb  = (const float*)d_in[15];
  const int* ti  = (const int*)d_in[16];
  const int* fi  = (const int*)d_in[17];
  const int* ri  = (const int*)d_in[18];
  const int* ei  = (const int*)d_in[19];
  const int* rni = (const int*)d_in[20];
  const int* sl  = (const int*)d_in[21];
  const int* cs  = (const int*)d_in[22];
  float* out = (float*)d_out;

  // --- ws layout (total ~2.5 MB) ---
  uint8_t* ws = (uint8_t*)d_ws;
  unsigned short* Bsw0    = (unsigned short*)(ws + 0);         // 262144 B
  unsigned short* Bsw1    = (unsigned short*)(ws + 262144);    // 262144 B
  float*          saved   = (float*)(ws + 524288);             // 131072 B
  float*          wbuf    = (float*)(ws + 655360);             // 786432 B
  int*            counts  = (int*)(ws + 1441792);              // 262144 B
  int*            offsets = (int*)(ws + 1703936);              // 262144 B
  int*            cursor  = (int*)(ws + 1966080);              // 262144 B
  unsigned short* edges   = (unsigned short*)(ws + 2228224);   // 393216 B

  hipMemsetAsync(counts, 0, BN*sizeof(int), stream);
  hipMemsetAsync(cursor, 0, BN*sizeof(int), stream);

  kswz<<<512, 64, 0, stream>>>(Wi0, Wh0, Wi1, Wh1, Bsw0, Bsw1);
  ksave<<<dim3(BB, 2), 512, 0, stream>>>(c0, h0, c1, h1, ei, rni, saved);

  // fused 2-layer LSTM, in place; skips done batches (they keep old states)
  klstm2<<<BN/ROWSB, 512, 0, stream>>>(ne, c0, h0, c1, h1, Bsw0, b0, Bsw1, b1, sl, cs);

  krestore<<<dim3(BB, 2), 512, 0, stream>>>(c0, h0, c1, h1, ei, rni, saved);

  // decisions + edge counting (fused former kcount)
  kdec<<<BN/4, 256, 0, stream>>>(c0, h0, c1, h1, Wr, br, Wb, bb, ip, ei, rni,
                                 ri, ti, fi, counts, wbuf);

  kscan<<<BB, 256, 0, stream>>>(counts, offsets);
  kfill<<<BN/256, 256, 0, stream>>>(ri, ti, fi, offsets, cursor, edges);

  kagg<<<BN, 128, 0, stream>>>(c0, h0, c1, h1, ip, wbuf, edges, counts, offsets,
                               sl, cs, out);
}

// Round 4
// 450.955 us; speedup vs baseline: 1.3139x; 1.0279x over previous
//
#include <hip/hip_runtime.h>
#include <stdint.h>

#define BB 32
#define NN 2048
#define HH 128
#define BN (BB*NN)

typedef short v8s __attribute__((ext_vector_type(8)));
typedef float v4f __attribute__((ext_vector_type(4)));

__device__ __forceinline__ unsigned short f2b(float f){
  union { float f; unsigned int i; } v; v.f = f;
  unsigned int x = v.i;
  unsigned int r = x + 0x7FFFu + ((x >> 16) & 1u);   // RNE f32 -> bf16
  return (unsigned short)(r >> 16);
}
__device__ __forceinline__ unsigned int pk2(float a, float b){
  return (unsigned int)f2b(a) | ((unsigned int)f2b(b) << 16);
}
__device__ __forceinline__ float frcp(float x){ return __builtin_amdgcn_rcpf(x); }
// fast sigmoid / tanh: v_exp + v_rcp, ~1e-6 rel err (<< bf16 gate noise)
__device__ __forceinline__ float fsigm(float x){ return frcp(1.0f + __expf(-x)); }
__device__ __forceinline__ float ftanh(float x){ return 1.0f - 2.0f*frcp(1.0f + __expf(2.0f*x)); }

// ---------------- pre-swizzle B = [Wi;Wh] (f32) into bf16 MFMA fragment order
// Bsw[((kc*32+ct)*64 + lane)*8 + j] = bf16(Bcat[kc*32 + (lane>>4)*8 + j][ct*16 + (lane&15)])
__global__ void kswz(const float* __restrict__ Wi0, const float* __restrict__ Wh0,
                     const float* __restrict__ Wi1, const float* __restrict__ Wh1,
                     unsigned short* __restrict__ Bsw0, unsigned short* __restrict__ Bsw1){
  int bid = blockIdx.x;            // 0..511
  int layer = bid >> 8;
  int kc = (bid >> 5) & 7;
  int ct = bid & 31;
  int lane = threadIdx.x;          // 0..63
  const float* Wi = layer ? Wi1 : Wi0;
  const float* Wh = layer ? Wh1 : Wh0;
  unsigned short* dst = layer ? Bsw1 : Bsw0;
  int col = ct*16 + (lane & 15);
  int kbase = kc*32 + (lane >> 4)*8;
  size_t o = ((size_t)(kc*32 + ct)*64 + (size_t)lane)*8;
  #pragma unroll
  for (int j = 0; j < 8; j++){
    int k = kbase + j;
    dst[o + j] = f2b((k < 128) ? Wi[k*512 + col] : Wh[(k-128)*512 + col]);
  }
}

// ---------------- fused 2-layer LSTM + decision head ------------------------
// Block: 32 rows, 512 threads (8 waves). Wave w owns channels w*16..w*16+15 of
// every gate. A tiles staged in LDS as bf16; h0_new -> separate LDS (ldsG).
// Epilogues keep c0n/h0n in regs; decision dot-products reduced via shfl+LDS.
// Global c/h stores are PREDICATED OFF at exit/raise NODE rows (replaces
// ksave/krestore). wbuf for those rows is fixed later by kpatch.
#define ROWSB 32
#define PA 264   // ushorts/row of A tile: 256 + 8 pad
#define PH 136   // ushorts/row of H tiles: 128 + 8 pad

__global__ __launch_bounds__(512, 4) void klstm2(
    const float* __restrict__ ne,
    float* __restrict__ c0, float* __restrict__ h0,
    float* __restrict__ c1, float* __restrict__ h1,
    const unsigned short* __restrict__ Bsw0, const float* __restrict__ b0,
    const unsigned short* __restrict__ Bsw1, const float* __restrict__ b1,
    const float* __restrict__ Wr, const float* __restrict__ br,
    const float* __restrict__ Wb, const float* __restrict__ bb,
    const float* __restrict__ ip,
    const int* __restrict__ exit_idx, const int* __restrict__ raise_idx,
    const int* __restrict__ ri, const int* __restrict__ ti, const int* __restrict__ fi,
    int* __restrict__ counts,
    float* __restrict__ wbuf,
    const int* __restrict__ step_limits, const int* __restrict__ cur_step)
{
  __shared__ unsigned short ldsA[ROWSB*PA];   // [ne | h0_old] bf16
  __shared__ unsigned short ldsH[ROWSB*PH];   // h1_old bf16
  __shared__ unsigned short ldsG[ROWSB*PH];   // h0_new bf16
  __shared__ float ldsR[ROWSB*8*4];           // decision partials [row][wid][4]

  int rowbase = blockIdx.x * ROWSB;           // 32 rows, never crosses a batch
  int b = rowbase >> 11;
  if (cur_step[0] >= step_limits[b]) return;  // done batch: keep old states

  int tid = threadIdx.x;
  int wid = tid >> 6, lane = tid & 63;
  int quad = lane >> 4, l16 = lane & 15;
  int ch = wid*16 + l16;            // channel within each gate (0..127)
  int e_row = exit_idx[b], r_row = raise_idx[b];   // NODE indices (0..2047)

  // ---- stage A0 = bf16([ne | h0_old]) : 4 float4 per thread ----
  #pragma unroll
  for (int p = 0; p < 4; p++){
    int idx = p*512 + tid;
    int row = idx >> 6, chunk = idx & 63;     // chunk = float4 index (0..63)
    size_t g = (size_t)(rowbase + row)*128 + (chunk & 31)*4;
    float4 v = (chunk < 32) ? *(const float4*)(ne + g) : *(const float4*)(h0 + g);
    uint2 w; w.x = pk2(v.x, v.y); w.y = pk2(v.z, v.w);
    *(uint2*)&ldsA[row*PA + chunk*4] = w;
  }
  // ---- stage H1 = bf16(h1_old) (consumed only after second barrier) ----
  #pragma unroll
  for (int p = 0; p < 2; p++){
    int idx = p*512 + tid;
    int row = idx >> 5, chunk = idx & 31;
    float4 v = *(const float4*)(h1 + (size_t)(rowbase + row)*128 + chunk*4);
    uint2 w; w.x = pk2(v.x, v.y); w.y = pk2(v.z, v.w);
    *(uint2*)&ldsH[row*PH + chunk*4] = w;
  }

  // ---- prefetch c0 rows + biases + first B frags (independent of LDS) ----
  float cpre[8], bias[4];
  #pragma unroll
  for (int rt = 0; rt < 2; rt++)
    #pragma unroll
    for (int r = 0; r < 4; r++)
      cpre[rt*4+r] = c0[((size_t)rowbase + rt*16 + quad*4 + r)*128 + ch];
  #pragma unroll
  for (int g = 0; g < 4; g++) bias[g] = b0[g*128 + ch];
  const v8s* Bv0 = (const v8s*)Bsw0;
  v8s bc[4], bn[4];
  #pragma unroll
  for (int g = 0; g < 4; g++) bc[g] = Bv0[(size_t)(g*8 + wid)*64 + lane];

  __syncthreads();

  // ================= layer 0: gates = [ne|h0_old] @ B0 =================
  v4f acc[2][4] = {};
  #pragma unroll
  for (int kc = 0; kc < 8; kc++){
    if (kc < 7){
      #pragma unroll
      for (int g = 0; g < 4; g++) bn[g] = Bv0[(size_t)((kc+1)*32 + g*8 + wid)*64 + lane];
    }
    v8s a0 = *(const v8s*)&ldsA[(0*16 + l16)*PA + kc*32 + quad*8];
    v8s a1 = *(const v8s*)&ldsA[(1*16 + l16)*PA + kc*32 + quad*8];
    #pragma unroll
    for (int g = 0; g < 4; g++){
      acc[0][g] = __builtin_amdgcn_mfma_f32_16x16x32_bf16(a0, bc[g], acc[0][g], 0,0,0);
      acc[1][g] = __builtin_amdgcn_mfma_f32_16x16x32_bf16(a1, bc[g], acc[1][g], 0,0,0);
    }
    #pragma unroll
    for (int g = 0; g < 4; g++) bc[g] = bn[g];
  }

  // ---- epilogue 0: LSTM update; keep c0n/h0n in regs; h0_new -> ldsG -------
  float cn0[8], hn0[8];
  #pragma unroll
  for (int rt = 0; rt < 2; rt++){
    #pragma unroll
    for (int r = 0; r < 4; r++){
      int k = rt*4 + r;
      int lrow = rt*16 + quad*4 + r;
      int grow = rowbase + lrow;
      int node = grow & 2047;                      // node index within batch
      bool special = (node == e_row) || (node == r_row);
      float iv = acc[rt][0][r] + bias[0];
      float fv = acc[rt][1][r] + bias[1];
      float gv = acc[rt][2][r] + bias[2];
      float ov = acc[rt][3][r] + bias[3];
      float cn = fsigm(fv)*cpre[k] + fsigm(iv)*ftanh(gv);
      float hn = fsigm(ov)*ftanh(cn);
      cn0[k] = cn; hn0[k] = hn;
      if (!special){
        c0[(size_t)grow*128 + ch] = cn;
        h0[(size_t)grow*128 + ch] = hn;
      }
      ldsG[lrow*PH + ch] = f2b(hn);   // layer-1 A operand (UNMASKED h0n, per ref)
    }
  }

  // ---- prefetch c1 rows + layer-1 bias + first B1 frags (pre-barrier) ----
  #pragma unroll
  for (int rt = 0; rt < 2; rt++)
    #pragma unroll
    for (int r = 0; r < 4; r++)
      cpre[rt*4+r] = c1[((size_t)rowbase + rt*16 + quad*4 + r)*128 + ch];
  #pragma unroll
  for (int g = 0; g < 4; g++) bias[g] = b1[g*128 + ch];
  const v8s* Bv1 = (const v8s*)Bsw1;
  #pragma unroll
  for (int g = 0; g < 4; g++) bc[g] = Bv1[(size_t)(g*8 + wid)*64 + lane];

  __syncthreads();   // h0_new + h1_old LDS tiles complete

  // ================= layer 1: gates = [h0_new | h1_old] @ B1 =================
  #pragma unroll
  for (int rt = 0; rt < 2; rt++)
    #pragma unroll
    for (int g = 0; g < 4; g++)
      acc[rt][g] = (v4f){0.f, 0.f, 0.f, 0.f};
  #pragma unroll
  for (int kc = 0; kc < 8; kc++){
    if (kc < 7){
      #pragma unroll
      for (int g = 0; g < 4; g++) bn[g] = Bv1[(size_t)((kc+1)*32 + g*8 + wid)*64 + lane];
    }
    v8s a0, a1;
    if (kc < 4){
      a0 = *(const v8s*)&ldsG[(0*16 + l16)*PH + kc*32 + quad*8];
      a1 = *(const v8s*)&ldsG[(1*16 + l16)*PH + kc*32 + quad*8];
    } else {
      a0 = *(const v8s*)&ldsH[(0*16 + l16)*PH + (kc-4)*32 + quad*8];
      a1 = *(const v8s*)&ldsH[(1*16 + l16)*PH + (kc-4)*32 + quad*8];
    }
    #pragma unroll
    for (int g = 0; g < 4; g++){
      acc[0][g] = __builtin_amdgcn_mfma_f32_16x16x32_bf16(a0, bc[g], acc[0][g], 0,0,0);
      acc[1][g] = __builtin_amdgcn_mfma_f32_16x16x32_bf16(a1, bc[g], acc[1][g], 0,0,0);
    }
    #pragma unroll
    for (int g = 0; g < 4; g++) bc[g] = bn[g];
  }

  // ---- decision weights for this thread's channel (2-col each, 4 blocks) ---
  float2 wrA = *(const float2*)&Wr[(      ch)*2];
  float2 wrB = *(const float2*)&Wr[(128 + ch)*2];
  float2 wrC = *(const float2*)&Wr[(256 + ch)*2];
  float2 wrD = *(const float2*)&Wr[(384 + ch)*2];
  float2 wbA = *(const float2*)&Wb[(      ch)*2];
  float2 wbB = *(const float2*)&Wb[(128 + ch)*2];
  float2 wbC = *(const float2*)&Wb[(256 + ch)*2];
  float2 wbD = *(const float2*)&Wb[(384 + ch)*2];

  // ---- epilogue 1 + decision partials ----
  #pragma unroll
  for (int rt = 0; rt < 2; rt++){
    #pragma unroll
    for (int r = 0; r < 4; r++){
      int k = rt*4 + r;
      int lrow = rt*16 + quad*4 + r;
      int grow = rowbase + lrow;
      int node = grow & 2047;                      // node index within batch
      bool special = (node == e_row) || (node == r_row);
      float iv = acc[rt][0][r] + bias[0];
      float fv = acc[rt][1][r] + bias[1];
      float gv = acc[rt][2][r] + bias[2];
      float ov = acc[rt][3][r] + bias[3];
      float cn = fsigm(fv)*cpre[k] + fsigm(iv)*ftanh(gv);
      float hn = fsigm(ov)*ftanh(cn);
      if (!special){
        c1[(size_t)grow*128 + ch] = cn;
        h1[(size_t)grow*128 + ch] = hn;
      }
      // decision partials over this thread's channel
      float p0 = cn0[k]*wrA.x + hn0[k]*wrB.x + cn*wrC.x + hn*wrD.x;
      float p1 = cn0[k]*wrA.y + hn0[k]*wrB.y + cn*wrC.y + hn*wrD.y;
      float p2 = cn0[k]*wbA.x + hn0[k]*wbB.x + cn*wbC.x + hn*wbD.x;
      float p3 = cn0[k]*wbA.y + hn0[k]*wbB.y + cn*wbC.y + hn*wbD.y;
      // reduce over the 16 channels of this wave (l16 group)
      #pragma unroll
      for (int off = 1; off < 16; off <<= 1){
        p0 += __shfl_xor(p0, off, 64);
        p1 += __shfl_xor(p1, off, 64);
        p2 += __shfl_xor(p2, off, 64);
        p3 += __shfl_xor(p3, off, 64);
      }
      if (l16 == 0){
        float4 pv = {p0, p1, p2, p3};
        *(float4*)&ldsR[(lrow*8 + wid)*4] = pv;
      }
    }
  }
  __syncthreads();

  // ---- finisher: 32 threads, one row each: cross-wave sum + softmax + wbuf
  if (tid < 32){
    int grow = rowbase + tid;
    float s0=0.f, s1=0.f, s2=0.f, s3=0.f;
    #pragma unroll
    for (int w = 0; w < 8; w++){
      float4 pv = *(const float4*)&ldsR[(tid*8 + w)*4];
      s0 += pv.x; s1 += pv.y; s2 += pv.z; s3 += pv.w;
    }
    float r0 = s0 + br[0], r1 = s1 + br[1];
    float q0 = s2 + bb[0], q1 = s3 + bb[1];
    float m = fmaxf(r0, r1);
    float e0 = __expf(r0 - m), e1 = __expf(r1 - m);
    float pr = e0 / (e0 + e1), pn = e1 / (e0 + e1);
    float m2 = fmaxf(q0, q1);
    float f0 = __expf(q0 - m2), f1 = __expf(q1 - m2);
    float pt = f0 / (f0 + f1), pf = f1 / (f0 + f1);
    float ipv = ip[grow];
    wbuf[0*BN + grow] = pr * ipv;
    wbuf[1*BN + grow] = pn * pt * ipv;
    wbuf[2*BN + grow] = pn * pf * ipv;
    // CSR edge counting (old kcount)
    atomicAdd(&counts[(b<<11) + ri[grow]], 1);
    atomicAdd(&counts[(b<<11) + ti[grow]], 1);
    atomicAdd(&counts[(b<<11) + fi[grow]], 1);
  }
}

// ---------------- patch decisions at exit/raise rows (need OLD states) ------
__global__ __launch_bounds__(64) void kpatch(
    const float* __restrict__ c0, const float* __restrict__ h0,
    const float* __restrict__ c1, const float* __restrict__ h1,
    const float* __restrict__ Wb, const float* __restrict__ bb,
    const float* __restrict__ ip,
    const int* __restrict__ exit_idx, const int* __restrict__ raise_idx,
    float* __restrict__ wbuf)
{
  int b = blockIdx.x;
  int idx = blockIdx.y ? raise_idx[b] : exit_idx[b];
  int gid = (b << 11) + idx;
  int lane = threadIdx.x;
  const float* bufs[4] = {c0, h0, c1, h1};
  const float* hb = bufs[lane >> 4] + (size_t)gid*128 + (lane & 15)*8;
  float4 hv0 = *(const float4*)hb;
  float4 hv1 = *(const float4*)(hb + 4);
  float hv[8] = {hv0.x, hv0.y, hv0.z, hv0.w, hv1.x, hv1.y, hv1.z, hv1.w};
  const float* wbp = Wb + lane*16;
  float q0=0.f, q1=0.f;
  #pragma unroll
  for (int j = 0; j < 8; j++){
    q0 += hv[j] * wbp[j*2];
    q1 += hv[j] * wbp[j*2+1];
  }
  #pragma unroll
  for (int off = 32; off > 0; off >>= 1){
    q0 += __shfl_xor(q0, off, 64);
    q1 += __shfl_xor(q1, off, 64);
  }
  if (lane == 0){
    q0 += bb[0]; q1 += bb[1];
    float m2 = fmaxf(q0, q1);
    float f0 = __expf(q0 - m2), f1 = __expf(q1 - m2);
    float pt = f0 / (f0 + f1), pf = f1 / (f0 + f1);
    float ipv = ip[gid];
    wbuf[0*BN + gid] = 0.f;          // raise_dec overridden to (0,1)
    wbuf[1*BN + gid] = pt * ipv;
    wbuf[2*BN + gid] = pf * ipv;
  }
}

// ---------------- CSR build: scan (also zeroes cursor) / fill ----------------
__global__ __launch_bounds__(256) void kscan(const int* __restrict__ counts,
                                             int* __restrict__ offsets,
                                             int* __restrict__ cursor){
  __shared__ int lds[256];
  int b = blockIdx.x, tid = threadIdx.x;
  const int* c = counts + b*NN;
  int* o = offsets + b*NN;
  int* cu = cursor + b*NN;
  int v[8]; int s = 0;
  #pragma unroll
  for (int i = 0; i < 8; i++){ v[i] = c[tid*8+i]; s += v[i]; cu[tid*8+i] = 0; }
  lds[tid] = s;
  __syncthreads();
  if (tid == 0){
    int run = 0;
    for (int t = 0; t < 256; t++){ int tmp = lds[t]; lds[t] = run; run += tmp; }
  }
  __syncthreads();
  int off = lds[tid];
  #pragma unroll
  for (int i = 0; i < 8; i++){ o[tid*8+i] = off; off += v[i]; }
}

__global__ void kfill(const int* __restrict__ ri, const int* __restrict__ ti,
                      const int* __restrict__ fi, const int* __restrict__ offsets,
                      int* __restrict__ cursor, unsigned short* __restrict__ edges){
  int gid = blockIdx.x*256 + threadIdx.x;
  int b = gid >> 11, n = gid & 2047;
  size_t ebase = (size_t)b*3*NN;
  int t0 = ri[gid]; int p0 = atomicAdd(&cursor[b*NN+t0], 1);
  edges[ebase + offsets[b*NN+t0] + p0] = (unsigned short)(n);
  int t1 = ti[gid]; int p1 = atomicAdd(&cursor[b*NN+t1], 1);
  edges[ebase + offsets[b*NN+t1] + p1] = (unsigned short)(n | (1<<11));
  int t2 = fi[gid]; int p2 = atomicAdd(&cursor[b*NN+t2], 1);
  edges[ebase + offsets[b*NN+t2] + p2] = (unsigned short)(n | (2<<11));
}

// ---------------- gather + normalize + output (all batches) -----------------
__global__ __launch_bounds__(128) void kagg(
    const float* __restrict__ c0, const float* __restrict__ h0,
    const float* __restrict__ c1, const float* __restrict__ h1,
    const float* __restrict__ ip,
    const float* __restrict__ wbuf, const unsigned short* __restrict__ edges,
    const int* __restrict__ counts, const int* __restrict__ offsets,
    const int* __restrict__ step_limits, const int* __restrict__ cur_step,
    float* __restrict__ out)
{
  int gid = blockIdx.x;            // b*N + j
  int b = gid >> 11;
  int tid = threadIdx.x;           // 0..127, channels tid*4..tid*4+3
  size_t obase = (size_t)gid*513;
  const float* bufs[4] = {c0, h0, c1, h1};

  if (cur_step[0] >= step_limits[b]){       // done: copy old state + old ip
    int c = tid*4;
    const float* s = bufs[c >> 7];
    size_t rb = (size_t)gid*128 + (c & 127);
    out[obase + c+0] = s[rb+0];
    out[obase + c+1] = s[rb+1];
    out[obase + c+2] = s[rb+2];
    out[obase + c+3] = s[rb+3];
    if (tid == 0) out[obase + 512] = ip[gid];
    return;
  }

  int cnt = counts[gid], off = offsets[gid];
  const unsigned short* eb = edges + (size_t)b*3*NN + off;
  const float* sb = bufs[tid >> 5];
  int coff = (tid & 31)*4;
  float a0=0.f, a1=0.f, a2=0.f, a3=0.f, ipn=0.f;
  for (int e = 0; e < cnt; e++){
    int pk = eb[e];
    int n = pk & 2047, et = pk >> 11;
    float w = wbuf[et*BN + (b<<11) + n];
    ipn += w;
    float4 sv = *(const float4*)(sb + ((size_t)(b<<11) + n)*128 + coff);
    a0 += w * sv.x;
    a1 += w * sv.y;
    a2 += w * sv.z;
    a3 += w * sv.w;
  }
  int c = tid*4;
  float inv = 1.0f / (ipn + 1e-7f);
  out[obase + c+0] = a0*inv;
  out[obase + c+1] = a1*inv;
  out[obase + c+2] = a2*inv;
  out[obase + c+3] = a3*inv;
  if (tid == 0) out[obase + 512] = ipn;
}

extern "C" void kernel_launch(void* const* d_in, const int* in_sizes, int n_in,
                              void* d_out, int out_size, void* d_ws, size_t ws_size,
                              hipStream_t stream){
  const float* ne  = (const float*)d_in[0];
  float* c0  = (float*)d_in[1];   // updated in place (harness restores before every launch)
  float* h0  = (float*)d_in[2];
  float* c1  = (float*)d_in[3];
  float* h1  = (float*)d_in[4];
  const float* ip  = (const float*)d_in[5];
  const float* Wi0 = (const float*)d_in[6];
  const float* Wh0 = (const float*)d_in[7];
  const float* b0  = (const float*)d_in[8];
  const float* Wi1 = (const float*)d_in[9];
  const float* Wh1 = (const float*)d_in[10];
  const float* b1  = (const float*)d_in[11];
  const float* Wr  = (const float*)d_in[12];
  const float* br  = (const float*)d_in[13];
  const float* Wb  = (const float*)d_in[14];
  const float* bb  = (const float*)d_in[15];
  const int* ti  = (const int*)d_in[16];
  const int* fi  = (const int*)d_in[17];
  const int* ri  = (const int*)d_in[18];
  const int* ei  = (const int*)d_in[19];
  const int* rni = (const int*)d_in[20];
  const int* sl  = (const int*)d_in[21];
  const int* cs  = (const int*)d_in[22];
  float* out = (float*)d_out;

  // --- ws layout ---
  uint8_t* ws = (uint8_t*)d_ws;
  unsigned short* Bsw0    = (unsigned short*)(ws + 0);         // 262144 B
  unsigned short* Bsw1    = (unsigned short*)(ws + 262144);    // 262144 B
  float*          wbuf    = (float*)(ws + 655360);             // 786432 B
  int*            counts  = (int*)(ws + 1441792);              // 262144 B
  int*            offsets = (int*)(ws + 1703936);              // 262144 B
  int*            cursor  = (int*)(ws + 1966080);              // 262144 B
  unsigned short* edges   = (unsigned short*)(ws + 2228224);   // 393216 B

  hipMemsetAsync(counts, 0, BN*sizeof(int), stream);

  kswz<<<512, 64, 0, stream>>>(Wi0, Wh0, Wi1, Wh1, Bsw0, Bsw1);

  // fused 2-layer LSTM + decision head; skips done batches; skips writes at
  // exit/raise rows (keeps old state there; replaces ksave/krestore)
  klstm2<<<BN/ROWSB, 512, 0, stream>>>(ne, c0, h0, c1, h1, Bsw0, b0, Bsw1, b1,
                                       Wr, br, Wb, bb, ip, ei, rni,
                                       ri, ti, fi, counts, wbuf, sl, cs);

  // fix decisions at exit/raise rows (branch softmax needs OLD states there)
  kpatch<<<dim3(BB, 2), 64, 0, stream>>>(c0, h0, c1, h1, Wb, bb, ip, ei, rni, wbuf);

  kscan<<<BB, 256, 0, stream>>>(counts, offsets, cursor);
  kfill<<<BN/256, 256, 0, stream>>>(ri, ti, fi, offsets, cursor, edges);

  kagg<<<BN, 128, 0, stream>>>(c0, h0, c1, h1, ip, wbuf, edges, counts, offsets,
                               sl, cs, out);
}